// Round 7
// baseline (218.509 us; speedup 1.0000x reference)
//
#include <hip/hip_runtime.h>

// B=8, S=2048, IN=1024, H=1024
//   q  = vec @ wq_w^T + wq_b            [B,S,H]
//   ret= relu(q_b^T q_b) per batch      [B,H,H]   (registers only)
//   out= ret @ lin_w + lin_b            [B,H]
//
// Pipeline:
//   prep:      out init + vec/wq fp32->bf16 (one launch)      [R4, known good]
//   gemm_q:    m97-style global_load_lds bf16 GEMM -> qT      [R2, known good]
//   syrk_wave: NEW — 1-wave blocks, private LDS, NO barriers. 4-deep LDS ring
//              (A0..A3/B0..B3), BK=64, prefetch dist 3 -> compiler-pipelined
//              vmcnt. Symmetric pairs (136) x 8 batches; batch = blockIdx&7
//              for XCD-L2 locality (4MB slice per XCD). Full K per block
//              (relu nonlinear -> K must finish in-block; R5 lesson).

#define BM 128
#define BN 128

typedef short     bf16x8 __attribute__((ext_vector_type(8)));
typedef unsigned short u16x8 __attribute__((ext_vector_type(8)));
typedef float     f32x4 __attribute__((ext_vector_type(4)));

__device__ inline unsigned short f2bf(float f) {
  unsigned int u = __float_as_uint(f);
  u += 0x7fffu + ((u >> 16) & 1u);   // RNE
  return (unsigned short)(u >> 16);
}

__device__ inline u16x8 pack8(float4 a, float4 b) {
  u16x8 r;
  r[0] = f2bf(a.x); r[1] = f2bf(a.y); r[2] = f2bf(a.z); r[3] = f2bf(a.w);
  r[4] = f2bf(b.x); r[5] = f2bf(b.y); r[6] = f2bf(b.z); r[7] = f2bf(b.w);
  return r;
}

__device__ inline void async16(void* lds, const void* g) {
  __builtin_amdgcn_global_load_lds(
      (const __attribute__((address_space(1))) void*)g,
      (__attribute__((address_space(3))) void*)lds,
      16, 0, 0);
}

// One launch: vec cvt (blocks 0..8191), wq cvt (blocks 8192..8703), out init
__global__ __launch_bounds__(256) void prep(
    const float* __restrict__ vec, unsigned short* __restrict__ vecbf,
    const float* __restrict__ wq,  unsigned short* __restrict__ wqbf,
    const float* __restrict__ lin_b, float* __restrict__ out)
{
  const int gid = blockIdx.x * 256 + threadIdx.x;
  if (blockIdx.x < 8192) {
    const float4* s = (const float4*)(vec + (size_t)gid * 8);
    float4 a = s[0], b = s[1];
    *(u16x8*)(vecbf + (size_t)gid * 8) = pack8(a, b);
    if (gid < 8192) out[gid] = lin_b[0];
  } else {
    const int i = gid - 8192 * 256;   // 0..131071
    const float4* s = (const float4*)(wq + (size_t)i * 8);
    float4 a = s[0], b = s[1];
    *(u16x8*)(wqbf + (size_t)i * 8) = pack8(a, b);
  }
}

__global__ void init_out(float* __restrict__ out, const float* __restrict__ lin_b) {
  int i = blockIdx.x * 256 + threadIdx.x;
  if (i < 8192) out[i] = lin_b[0];
}

// ---------------- gemm_q (m97-style): qT = wqbf * vecbf^T + bias ----------------
__global__ __launch_bounds__(256) void gemm_q(
    const unsigned short* __restrict__ A, const unsigned short* __restrict__ Bm,
    const float* __restrict__ bias, unsigned short* __restrict__ qT)
{
  __shared__ unsigned short As[BM * 32];
  __shared__ unsigned short Bs[BN * 32];

  const int m0 = blockIdx.y * BM;
  const int n0 = blockIdx.x * BN;
  const int t    = threadIdx.x;
  const int lane = t & 63;
  const int wave = t >> 6;
  const int wm = (wave >> 1) * 64;
  const int wn = (wave & 1) * 64;
  const int quad = lane >> 4;
  const int lrow = lane & 15;

  const int srow = t >> 2;                               // 0..63
  const int gcol = (((t & 3) ^ ((srow >> 1) & 3)) << 3); // swizzled col (shorts)
  const unsigned short* gA0 = A  + (size_t)(m0 + srow) * 1024 + gcol;
  const unsigned short* gA1 = gA0 + (size_t)64 * 1024;
  const unsigned short* gB0 = Bm + (size_t)(n0 + srow) * 1024 + gcol;
  const unsigned short* gB1 = gB0 + (size_t)64 * 1024;

  const int rc = (quad ^ ((lrow >> 1) & 3)) << 3;        // shorts

  f32x4 acc[4][4];
#pragma unroll
  for (int i = 0; i < 4; ++i)
#pragma unroll
    for (int j = 0; j < 4; ++j) acc[i][j] = (f32x4){0.f, 0.f, 0.f, 0.f};

  for (int k0 = 0; k0 < 1024; k0 += 32) {
    async16(&As[t * 8],        gA0 + k0);
    async16(&As[2048 + t * 8], gA1 + k0);
    async16(&Bs[t * 8],        gB0 + k0);
    async16(&Bs[2048 + t * 8], gB1 + k0);
    __syncthreads();

    bf16x8 af[4], bfr[4];
#pragma unroll
    for (int i = 0; i < 4; ++i)
      af[i] = *(const bf16x8*)&As[(wm + i * 16 + lrow) * 32 + rc];
#pragma unroll
    for (int j = 0; j < 4; ++j)
      bfr[j] = *(const bf16x8*)&Bs[(wn + j * 16 + lrow) * 32 + rc];
#pragma unroll
    for (int i = 0; i < 4; ++i)
#pragma unroll
      for (int j = 0; j < 4; ++j)
        acc[i][j] = __builtin_amdgcn_mfma_f32_16x16x32_bf16(af[i], bfr[j], acc[i][j], 0, 0, 0);
    __syncthreads();
  }

#pragma unroll
  for (int i = 0; i < 4; ++i) {
    const int mb = m0 + wm + i * 16 + quad * 4;
#pragma unroll
    for (int r = 0; r < 4; ++r) {
      const float bv = bias[mb + r];
#pragma unroll
      for (int j = 0; j < 4; ++j) {
        const int n = n0 + wn + j * 16 + lrow;
        qT[(size_t)(mb + r) * 16384 + n] = f2bf(acc[i][j][r] + bv);
      }
    }
  }
}

// ------- fallback gemm_q (fused fp32->bf16 inline), used if ws too small -------
__global__ __launch_bounds__(256) void gemm_q_fused(
    const float* __restrict__ Wq, const float* __restrict__ V,
    const float* __restrict__ bias, unsigned short* __restrict__ qT)
{
  __shared__ unsigned short As[BM * 32];
  __shared__ unsigned short Bs[BN * 32];

  const int m0 = blockIdx.y * BM;
  const int n0 = blockIdx.x * BN;
  const int t    = threadIdx.x;
  const int lane = t & 63;
  const int wave = t >> 6;
  const int wm = (wave >> 1) * 64;
  const int wn = (wave & 1) * 64;
  const int quad = lane >> 4;
  const int lrow = lane & 15;

  const int sr = t >> 1;
  const int sc = (t & 1) << 4;
  const float* gA = Wq + (size_t)(m0 + sr) * 1024 + sc;
  const float* gB = V  + (size_t)(n0 + sr) * 1024 + sc;

  f32x4 acc[4][4];
#pragma unroll
  for (int i = 0; i < 4; ++i)
#pragma unroll
    for (int j = 0; j < 4; ++j) acc[i][j] = (f32x4){0.f, 0.f, 0.f, 0.f};

  for (int k0 = 0; k0 < 1024; k0 += 32) {
    const float4* a4 = (const float4*)(gA + k0);
    const float4* b4 = (const float4*)(gB + k0);
    float4 av0 = a4[0], av1 = a4[1], av2 = a4[2], av3 = a4[3];
    float4 bv0 = b4[0], bv1 = b4[1], bv2 = b4[2], bv3 = b4[3];
    *(u16x8*)&As[sr * 32 + sc]     = pack8(av0, av1);
    *(u16x8*)&As[sr * 32 + sc + 8] = pack8(av2, av3);
    *(u16x8*)&Bs[sr * 32 + sc]     = pack8(bv0, bv1);
    *(u16x8*)&Bs[sr * 32 + sc + 8] = pack8(bv2, bv3);
    __syncthreads();

    bf16x8 af[4], bfr[4];
#pragma unroll
    for (int i = 0; i < 4; ++i)
      af[i] = *(const bf16x8*)&As[(wm + i * 16 + lrow) * 32 + quad * 8];
#pragma unroll
    for (int j = 0; j < 4; ++j)
      bfr[j] = *(const bf16x8*)&Bs[(wn + j * 16 + lrow) * 32 + quad * 8];
#pragma unroll
    for (int i = 0; i < 4; ++i)
#pragma unroll
      for (int j = 0; j < 4; ++j)
        acc[i][j] = __builtin_amdgcn_mfma_f32_16x16x32_bf16(af[i], bfr[j], acc[i][j], 0, 0, 0);
    __syncthreads();
  }

#pragma unroll
  for (int i = 0; i < 4; ++i) {
    const int mb = m0 + wm + i * 16 + quad * 4;
#pragma unroll
    for (int r = 0; r < 4; ++r) {
      const float bv = bias[mb + r];
#pragma unroll
      for (int j = 0; j < 4; ++j) {
        const int n = n0 + wn + j * 16 + lrow;
        qT[(size_t)(mb + r) * 16384 + n] = f2bf(acc[i][j][r] + bv);
      }
    }
  }
}

// ------------- syrk_wave: 1-wave blocks, private LDS, no barriers -------------
// blockIdx.x = pair*8 + batch; pair in [0,136): (tx,ty) ty<=tx over 16 64-tiles.
// 4-deep LDS ring, BK=64. Global chunk XOR-swizzled into lane-linear LDS.
__global__ __launch_bounds__(64) void syrk_wave(
    const unsigned short* __restrict__ qT, const float* __restrict__ W,
    float* __restrict__ out)
{
  __shared__ unsigned short A0[4096], A1[4096], A2[4096], A3[4096];
  __shared__ unsigned short B0[4096], B1[4096], B2[4096], B3[4096];

  const int bb  = blockIdx.x & 7;
  const int job = blockIdx.x >> 3;            // 0..135
  int tx = 0;
  while ((tx + 1) * (tx + 2) / 2 <= job) ++tx;
  const int ty = job - tx * (tx + 1) / 2;
  const int x0 = tx * 64, y0 = ty * 64;
  const bool diag = (tx == ty);

  const int lane = threadIdx.x;
  const int quad = lane >> 4;
  const int lrow = lane & 15;

  // staging: issue p covers rows p*8 + (lane>>3); global 8-short chunk
  // g = (lane&7) ^ ((lane>>3)&7) goes to LDS slot lane&7 (lane-linear dest).
  const int srow = lane >> 3;                               // 0..7
  const int gch  = (lane & 7) ^ srow;                       // 0..7
  const size_t cb = (size_t)bb * 2048 + gch * 8;
  const unsigned short* gA = qT + (size_t)(x0 + srow) * 16384 + cb;
  const unsigned short* gB = qT + (size_t)(y0 + srow) * 16384 + cb;

  f32x4 acc[4][4];
#pragma unroll
  for (int i = 0; i < 4; ++i)
#pragma unroll
    for (int j = 0; j < 4; ++j) acc[i][j] = (f32x4){0.f, 0.f, 0.f, 0.f};

  auto stage = [&](int c, unsigned short* Ab, unsigned short* Bb) {
#pragma unroll
    for (int p = 0; p < 8; ++p)
      async16(&Ab[p * 512 + lane * 8], gA + (size_t)p * 8 * 16384 + c * 64);
#pragma unroll
    for (int p = 0; p < 8; ++p)
      async16(&Bb[p * 512 + lane * 8], gB + (size_t)p * 8 * 16384 + c * 64);
  };

  auto compute = [&](const unsigned short* Ab, const unsigned short* Bb) {
#pragma unroll
    for (int kk = 0; kk < 2; ++kk) {
      const int sl = (((kk * 4 + quad) ^ (lrow & 7)) << 3);  // slot (shorts)
      bf16x8 af[4], bfr[4];
#pragma unroll
      for (int i = 0; i < 4; ++i)
        af[i] = *(const bf16x8*)&Ab[(i * 16 + lrow) * 64 + sl];
#pragma unroll
      for (int j = 0; j < 4; ++j)
        bfr[j] = *(const bf16x8*)&Bb[(j * 16 + lrow) * 64 + sl];
#pragma unroll
      for (int i = 0; i < 4; ++i)
#pragma unroll
        for (int j = 0; j < 4; ++j)
          acc[i][j] = __builtin_amdgcn_mfma_f32_16x16x32_bf16(af[i], bfr[j], acc[i][j], 0, 0, 0);
    }
  };

  // 4-deep software pipeline over 32 chunks of K=64 (full K=2048 in-block)
  stage(0, A0, B0);
  stage(1, A1, B1);
  stage(2, A2, B2);
  for (int c = 0; c < 32; c += 4) {
    compute(A0, B0); if (c + 3 < 32) stage(c + 3, A3, B3);
    compute(A1, B1); if (c + 4 < 32) stage(c + 4, A0, B0);
    compute(A2, B2); if (c + 5 < 32) stage(c + 5, A1, B1);
    compute(A3, B3); if (c + 6 < 32) stage(c + 6, A2, B2);
  }

  float* ob = out + bb * 1024;

  // row pass: out[x] += sum_y relu(C[x,y]) * W[y]
  float wv[4];
#pragma unroll
  for (int j = 0; j < 4; ++j) wv[j] = W[y0 + j * 16 + lrow];

#pragma unroll
  for (int i = 0; i < 4; ++i) {
#pragma unroll
    for (int r = 0; r < 4; ++r) {
      float p = 0.f;
#pragma unroll
      for (int j = 0; j < 4; ++j) {
        float v = acc[i][j][r];
        v = v > 0.f ? v : 0.f;
        p += v * wv[j];
      }
#pragma unroll
      for (int off = 1; off < 16; off <<= 1) p += __shfl_xor(p, off, 64);
      if (lrow == 0)
        atomicAdd(&ob[x0 + i * 16 + quad * 4 + r], p);
    }
  }

  // col pass (off-diagonal only): out[y] += sum_x relu(C[x,y]) * W[x]
  if (!diag) {
    float wx[4][4];
#pragma unroll
    for (int i = 0; i < 4; ++i)
#pragma unroll
      for (int r = 0; r < 4; ++r)
        wx[i][r] = W[x0 + i * 16 + quad * 4 + r];

#pragma unroll
    for (int j = 0; j < 4; ++j) {
      float pc = 0.f;
#pragma unroll
      for (int i = 0; i < 4; ++i)
#pragma unroll
        for (int r = 0; r < 4; ++r) {
          float v = acc[i][j][r];
          v = v > 0.f ? v : 0.f;
          pc += v * wx[i][r];
        }
      pc += __shfl_xor(pc, 16, 64);
      pc += __shfl_xor(pc, 32, 64);
      if (quad == 0)
        atomicAdd(&ob[y0 + j * 16 + lrow], pc);
    }
  }
}

extern "C" void kernel_launch(void* const* d_in, const int* in_sizes, int n_in,
                              void* d_out, int out_size, void* d_ws, size_t ws_size,
                              hipStream_t stream) {
  const float* vec   = (const float*)d_in[0];  // [8,2048,1024]
  const float* wq_w  = (const float*)d_in[1];  // [1024,1024]
  const float* wq_b  = (const float*)d_in[2];  // [1024]
  const float* lin_w = (const float*)d_in[3];  // [1,1024]
  const float* lin_b = (const float*)d_in[4];  // [1]
  float* out = (float*)d_out;                  // [8,1024]

  unsigned short* qT = (unsigned short*)d_ws;                    // 32 MiB
  const size_t need = (size_t)(32 + 32 + 2) * 1024 * 1024;

  if (ws_size >= need) {
    unsigned short* vecbf = qT + (size_t)16 * 1024 * 1024;       // 32 MiB
    unsigned short* wqbf  = vecbf + (size_t)16 * 1024 * 1024;    // 2 MiB
    prep<<<dim3(8192 + 512), dim3(256), 0, stream>>>(vec, vecbf, wq_w, wqbf, lin_b, out);
    gemm_q<<<dim3(128, 8), dim3(256), 0, stream>>>(wqbf, vecbf, wq_b, qT);
  } else {
    init_out<<<dim3(32), dim3(256), 0, stream>>>(out, lin_b);
    gemm_q_fused<<<dim3(128, 8), dim3(256), 0, stream>>>(wq_w, vec, wq_b, qT);
  }
  syrk_wave<<<dim3(136 * 8), dim3(64), 0, stream>>>(qT, lin_w, out);
}

// Round 8
// 189.660 us; speedup vs baseline: 1.1521x; 1.1521x over previous
//
#include <hip/hip_runtime.h>

// B=8, S=2048, IN=1024, H=1024
//   q  = vec @ wq_w^T + wq_b            [B,S,H]
//   ret= relu(q_b^T q_b) per batch      [B,H,H]   (registers only)
//   out= ret @ lin_w + lin_b            [B,H]
//
// Pipeline:
//   prep:      out init + vec/wq fp32->bf16 (one launch)
//   gemm_q:    m97-style global_load_lds bf16 GEMM -> qT       [known good]
//   syrk_half: symmetric pairs (ty<=tx) split along y into 128x64 half-jobs
//              (FULL K per block — relu nonlinear, K-split illegal, R5).
//              576 blocks = 2.25/CU, 24KB LDS -> multi-block co-residency.
//              R7 lesson: keep 4-wave blocks + barriers; TLP hides the drain.

#define BM 128
#define BN 128

typedef short     bf16x8 __attribute__((ext_vector_type(8)));
typedef unsigned short u16x8 __attribute__((ext_vector_type(8)));
typedef float     f32x4 __attribute__((ext_vector_type(4)));

__device__ inline unsigned short f2bf(float f) {
  unsigned int u = __float_as_uint(f);
  u += 0x7fffu + ((u >> 16) & 1u);   // RNE
  return (unsigned short)(u >> 16);
}

__device__ inline u16x8 pack8(float4 a, float4 b) {
  u16x8 r;
  r[0] = f2bf(a.x); r[1] = f2bf(a.y); r[2] = f2bf(a.z); r[3] = f2bf(a.w);
  r[4] = f2bf(b.x); r[5] = f2bf(b.y); r[6] = f2bf(b.z); r[7] = f2bf(b.w);
  return r;
}

__device__ inline void async16(void* lds, const void* g) {
  __builtin_amdgcn_global_load_lds(
      (const __attribute__((address_space(1))) void*)g,
      (__attribute__((address_space(3))) void*)lds,
      16, 0, 0);
}

// One launch: vec cvt (blocks 0..8191), wq cvt (blocks 8192..8703), out init
__global__ __launch_bounds__(256) void prep(
    const float* __restrict__ vec, unsigned short* __restrict__ vecbf,
    const float* __restrict__ wq,  unsigned short* __restrict__ wqbf,
    const float* __restrict__ lin_b, float* __restrict__ out)
{
  const int gid = blockIdx.x * 256 + threadIdx.x;
  if (blockIdx.x < 8192) {
    const float4* s = (const float4*)(vec + (size_t)gid * 8);
    float4 a = s[0], b = s[1];
    *(u16x8*)(vecbf + (size_t)gid * 8) = pack8(a, b);
    if (gid < 8192) out[gid] = lin_b[0];
  } else {
    const int i = gid - 8192 * 256;   // 0..131071
    const float4* s = (const float4*)(wq + (size_t)i * 8);
    float4 a = s[0], b = s[1];
    *(u16x8*)(wqbf + (size_t)i * 8) = pack8(a, b);
  }
}

__global__ void init_out(float* __restrict__ out, const float* __restrict__ lin_b) {
  int i = blockIdx.x * 256 + threadIdx.x;
  if (i < 8192) out[i] = lin_b[0];
}

// ---------------- gemm_q (m97-style): qT = wqbf * vecbf^T + bias ----------------
__global__ __launch_bounds__(256) void gemm_q(
    const unsigned short* __restrict__ A, const unsigned short* __restrict__ Bm,
    const float* __restrict__ bias, unsigned short* __restrict__ qT)
{
  __shared__ unsigned short As[BM * 32];
  __shared__ unsigned short Bs[BN * 32];

  const int m0 = blockIdx.y * BM;
  const int n0 = blockIdx.x * BN;
  const int t    = threadIdx.x;
  const int lane = t & 63;
  const int wave = t >> 6;
  const int wm = (wave >> 1) * 64;
  const int wn = (wave & 1) * 64;
  const int quad = lane >> 4;
  const int lrow = lane & 15;

  const int srow = t >> 2;                               // 0..63
  const int gcol = (((t & 3) ^ ((srow >> 1) & 3)) << 3); // swizzled col (shorts)
  const unsigned short* gA0 = A  + (size_t)(m0 + srow) * 1024 + gcol;
  const unsigned short* gA1 = gA0 + (size_t)64 * 1024;
  const unsigned short* gB0 = Bm + (size_t)(n0 + srow) * 1024 + gcol;
  const unsigned short* gB1 = gB0 + (size_t)64 * 1024;

  const int rc = (quad ^ ((lrow >> 1) & 3)) << 3;        // shorts

  f32x4 acc[4][4];
#pragma unroll
  for (int i = 0; i < 4; ++i)
#pragma unroll
    for (int j = 0; j < 4; ++j) acc[i][j] = (f32x4){0.f, 0.f, 0.f, 0.f};

  for (int k0 = 0; k0 < 1024; k0 += 32) {
    async16(&As[t * 8],        gA0 + k0);
    async16(&As[2048 + t * 8], gA1 + k0);
    async16(&Bs[t * 8],        gB0 + k0);
    async16(&Bs[2048 + t * 8], gB1 + k0);
    __syncthreads();

    bf16x8 af[4], bfr[4];
#pragma unroll
    for (int i = 0; i < 4; ++i)
      af[i] = *(const bf16x8*)&As[(wm + i * 16 + lrow) * 32 + rc];
#pragma unroll
    for (int j = 0; j < 4; ++j)
      bfr[j] = *(const bf16x8*)&Bs[(wn + j * 16 + lrow) * 32 + rc];
#pragma unroll
    for (int i = 0; i < 4; ++i)
#pragma unroll
      for (int j = 0; j < 4; ++j)
        acc[i][j] = __builtin_amdgcn_mfma_f32_16x16x32_bf16(af[i], bfr[j], acc[i][j], 0, 0, 0);
    __syncthreads();
  }

#pragma unroll
  for (int i = 0; i < 4; ++i) {
    const int mb = m0 + wm + i * 16 + quad * 4;
#pragma unroll
    for (int r = 0; r < 4; ++r) {
      const float bv = bias[mb + r];
#pragma unroll
      for (int j = 0; j < 4; ++j) {
        const int n = n0 + wn + j * 16 + lrow;
        qT[(size_t)(mb + r) * 16384 + n] = f2bf(acc[i][j][r] + bv);
      }
    }
  }
}

// ------- fallback gemm_q (fused fp32->bf16 inline), used if ws too small -------
__global__ __launch_bounds__(256) void gemm_q_fused(
    const float* __restrict__ Wq, const float* __restrict__ V,
    const float* __restrict__ bias, unsigned short* __restrict__ qT)
{
  __shared__ unsigned short As[BM * 32];
  __shared__ unsigned short Bs[BN * 32];

  const int m0 = blockIdx.y * BM;
  const int n0 = blockIdx.x * BN;
  const int t    = threadIdx.x;
  const int lane = t & 63;
  const int wave = t >> 6;
  const int wm = (wave >> 1) * 64;
  const int wn = (wave & 1) * 64;
  const int quad = lane >> 4;
  const int lrow = lane & 15;

  const int sr = t >> 1;
  const int sc = (t & 1) << 4;
  const float* gA = Wq + (size_t)(m0 + sr) * 1024 + sc;
  const float* gB = V  + (size_t)(n0 + sr) * 1024 + sc;

  f32x4 acc[4][4];
#pragma unroll
  for (int i = 0; i < 4; ++i)
#pragma unroll
    for (int j = 0; j < 4; ++j) acc[i][j] = (f32x4){0.f, 0.f, 0.f, 0.f};

  for (int k0 = 0; k0 < 1024; k0 += 32) {
    const float4* a4 = (const float4*)(gA + k0);
    const float4* b4 = (const float4*)(gB + k0);
    float4 av0 = a4[0], av1 = a4[1], av2 = a4[2], av3 = a4[3];
    float4 bv0 = b4[0], bv1 = b4[1], bv2 = b4[2], bv3 = b4[3];
    *(u16x8*)&As[sr * 32 + sc]     = pack8(av0, av1);
    *(u16x8*)&As[sr * 32 + sc + 8] = pack8(av2, av3);
    *(u16x8*)&Bs[sr * 32 + sc]     = pack8(bv0, bv1);
    *(u16x8*)&Bs[sr * 32 + sc + 8] = pack8(bv2, bv3);
    __syncthreads();

    bf16x8 af[4], bfr[4];
#pragma unroll
    for (int i = 0; i < 4; ++i)
      af[i] = *(const bf16x8*)&As[(wm + i * 16 + lrow) * 32 + quad * 8];
#pragma unroll
    for (int j = 0; j < 4; ++j)
      bfr[j] = *(const bf16x8*)&Bs[(wn + j * 16 + lrow) * 32 + quad * 8];
#pragma unroll
    for (int i = 0; i < 4; ++i)
#pragma unroll
      for (int j = 0; j < 4; ++j)
        acc[i][j] = __builtin_amdgcn_mfma_f32_16x16x32_bf16(af[i], bfr[j], acc[i][j], 0, 0, 0);
    __syncthreads();
  }

#pragma unroll
  for (int i = 0; i < 4; ++i) {
    const int mb = m0 + wm + i * 16 + quad * 4;
#pragma unroll
    for (int r = 0; r < 4; ++r) {
      const float bv = bias[mb + r];
#pragma unroll
      for (int j = 0; j < 4; ++j) {
        const int n = n0 + wn + j * 16 + lrow;
        qT[(size_t)(mb + r) * 16384 + n] = f2bf(acc[i][j][r] + bv);
      }
    }
  }
}

// ---------- syrk_half: symmetric pairs, y-split into 128x64, FULL K ----------
// blockIdx.x in [0,72): pair = x>>1 (ty<=tx over 8 128-tiles), yh = x&1.
// Block computes C[x0..x0+128, y0..y0+64] over K=2048; row pass for out[x],
// col pass (off-diag pairs) for out[y] via symmetry.
__global__ __launch_bounds__(256) void syrk_half(
    const unsigned short* __restrict__ qT, const float* __restrict__ W,
    float* __restrict__ out)
{
  __shared__ unsigned short As[128 * 64];   // 16 KB
  __shared__ unsigned short Bs[64 * 64];    // 8 KB

  const int bb  = blockIdx.z;
  const int pair = blockIdx.x >> 1;
  const int yh   = blockIdx.x & 1;
  int tx = 0;
  while ((tx + 1) * (tx + 2) / 2 <= pair) ++tx;
  const int ty = pair - tx * (tx + 1) / 2;
  const int x0 = tx * 128;
  const int y0 = ty * 128 + yh * 64;
  const bool diag = (tx == ty);

  const int t    = threadIdx.x;
  const int lane = t & 63;
  const int wave = t >> 6;
  const int wm = (wave >> 1) * 64;   // x offset of wave: 0 or 64
  const int wn = (wave & 1) * 32;    // y offset of wave: 0 or 32
  const int quad = lane >> 4;
  const int lrow = lane & 15;

  // staging: issue p covers rows p*32 + (t>>3); global chunk XOR-swizzled
  const int srow = t >> 3;                              // 0..31
  const int gcol = (((t & 7) ^ (srow & 7)) << 3);       // shorts
  const size_t cbase = (size_t)bb * 2048 + gcol;
  const unsigned short* gA = qT + (size_t)(x0 + srow) * 16384 + cbase;
  const unsigned short* gB = qT + (size_t)(y0 + srow) * 16384 + cbase;

  f32x4 acc[4][2];
#pragma unroll
  for (int i = 0; i < 4; ++i)
#pragma unroll
    for (int j = 0; j < 2; ++j) acc[i][j] = (f32x4){0.f, 0.f, 0.f, 0.f};

  for (int k0 = 0; k0 < 2048; k0 += 64) {
#pragma unroll
    for (int p = 0; p < 4; ++p)
      async16(&As[p * 2048 + t * 8], gA + (size_t)p * 32 * 16384 + k0);
#pragma unroll
    for (int p = 0; p < 2; ++p)
      async16(&Bs[p * 2048 + t * 8], gB + (size_t)p * 32 * 16384 + k0);
    __syncthreads();

#pragma unroll
    for (int kk = 0; kk < 2; ++kk) {
      const int rc = (((kk * 4 + quad) ^ (lrow & 7)) << 3);  // shorts
      bf16x8 af[4], bfr[2];
#pragma unroll
      for (int i = 0; i < 4; ++i)
        af[i] = *(const bf16x8*)&As[(wm + i * 16 + lrow) * 64 + rc];
#pragma unroll
      for (int j = 0; j < 2; ++j)
        bfr[j] = *(const bf16x8*)&Bs[(wn + j * 16 + lrow) * 64 + rc];
#pragma unroll
      for (int i = 0; i < 4; ++i)
#pragma unroll
        for (int j = 0; j < 2; ++j)
          acc[i][j] = __builtin_amdgcn_mfma_f32_16x16x32_bf16(af[i], bfr[j], acc[i][j], 0, 0, 0);
    }
    __syncthreads();
  }

  float* ob = out + bb * 1024;

  // row pass: out[x] += sum_y relu(C[x,y]) * W[y]   (partial over this y-half)
  float wv[2];
#pragma unroll
  for (int j = 0; j < 2; ++j) wv[j] = W[y0 + wn + j * 16 + lrow];

#pragma unroll
  for (int i = 0; i < 4; ++i) {
#pragma unroll
    for (int r = 0; r < 4; ++r) {
      float p = 0.f;
#pragma unroll
      for (int j = 0; j < 2; ++j) {
        float v = acc[i][j][r];
        v = v > 0.f ? v : 0.f;
        p += v * wv[j];
      }
#pragma unroll
      for (int off = 1; off < 16; off <<= 1) p += __shfl_xor(p, off, 64);
      if (lrow == 0)
        atomicAdd(&ob[x0 + wm + i * 16 + quad * 4 + r], p);
    }
  }

  // col pass (off-diagonal pairs only): out[y] += sum_x relu(C[x,y]) * W[x]
  if (!diag) {
    float wx[4][4];
#pragma unroll
    for (int i = 0; i < 4; ++i)
#pragma unroll
      for (int r = 0; r < 4; ++r)
        wx[i][r] = W[x0 + wm + i * 16 + quad * 4 + r];

#pragma unroll
    for (int j = 0; j < 2; ++j) {
      float pc = 0.f;
#pragma unroll
      for (int i = 0; i < 4; ++i)
#pragma unroll
        for (int r = 0; r < 4; ++r) {
          float v = acc[i][j][r];
          v = v > 0.f ? v : 0.f;
          pc += v * wx[i][r];
        }
      pc += __shfl_xor(pc, 16, 64);
      pc += __shfl_xor(pc, 32, 64);
      if (quad == 0)
        atomicAdd(&ob[y0 + wn + j * 16 + lrow], pc);
    }
  }
}

extern "C" void kernel_launch(void* const* d_in, const int* in_sizes, int n_in,
                              void* d_out, int out_size, void* d_ws, size_t ws_size,
                              hipStream_t stream) {
  const float* vec   = (const float*)d_in[0];  // [8,2048,1024]
  const float* wq_w  = (const float*)d_in[1];  // [1024,1024]
  const float* wq_b  = (const float*)d_in[2];  // [1024]
  const float* lin_w = (const float*)d_in[3];  // [1,1024]
  const float* lin_b = (const float*)d_in[4];  // [1]
  float* out = (float*)d_out;                  // [8,1024]

  unsigned short* qT = (unsigned short*)d_ws;                    // 32 MiB
  const size_t need = (size_t)(32 + 32 + 2) * 1024 * 1024;

  if (ws_size >= need) {
    unsigned short* vecbf = qT + (size_t)16 * 1024 * 1024;       // 32 MiB
    unsigned short* wqbf  = vecbf + (size_t)16 * 1024 * 1024;    // 2 MiB
    prep<<<dim3(8192 + 512), dim3(256), 0, stream>>>(vec, vecbf, wq_w, wqbf, lin_b, out);
    gemm_q<<<dim3(128, 8), dim3(256), 0, stream>>>(wqbf, vecbf, wq_b, qT);
  } else {
    init_out<<<dim3(32), dim3(256), 0, stream>>>(out, lin_b);
    gemm_q_fused<<<dim3(128, 8), dim3(256), 0, stream>>>(wq_w, vec, wq_b, qT);
  }
  syrk_half<<<dim3(72, 1, 8), dim3(256), 0, stream>>>(qT, lin_w, out);
}

// Round 9
// 180.632 us; speedup vs baseline: 1.2097x; 1.0500x over previous
//
#include <hip/hip_runtime.h>

// B=8, S=2048, IN=1024, H=1024
//   q  = vec @ wq_w^T + wq_b            [B,S,H]
//   ret= relu(q_b^T q_b) per batch      [B,H,H]   (registers only)
//   out= ret @ lin_w + lin_b            [B,H]
//
// Pipeline:
//   prep:       out init + vec/wq fp32->bf16 (one launch)
//   gemm_q:     m97-style bf16 GEMM; epilogue stores qT as FP8 e4m3 (qT is
//               consumed only by syrk; q~N(0,1) -> quantization error ~2%).
//   syrk_half8: symmetric pairs, y-split 128x64, FULL K (relu: K-split illegal).
//               fp8 staging: half the bytes, 12KB LDS, 3 async issues/iter.

#define BM 128
#define BN 128

typedef short     bf16x8 __attribute__((ext_vector_type(8)));
typedef unsigned short u16x8 __attribute__((ext_vector_type(8)));
typedef float     f32x4 __attribute__((ext_vector_type(4)));
typedef long long i64;

__device__ inline unsigned short f2bf(float f) {
  unsigned int u = __float_as_uint(f);
  u += 0x7fffu + ((u >> 16) & 1u);   // RNE
  return (unsigned short)(u >> 16);
}

__device__ inline u16x8 pack8(float4 a, float4 b) {
  u16x8 r;
  r[0] = f2bf(a.x); r[1] = f2bf(a.y); r[2] = f2bf(a.z); r[3] = f2bf(a.w);
  r[4] = f2bf(b.x); r[5] = f2bf(b.y); r[6] = f2bf(b.z); r[7] = f2bf(b.w);
  return r;
}

__device__ inline unsigned char f2fp8(float v) {
  int pk = __builtin_amdgcn_cvt_pk_fp8_f32(v, v, 0, false);  // RNE, OCP e4m3
  return (unsigned char)(pk & 0xff);
}

__device__ inline void async16(void* lds, const void* g) {
  __builtin_amdgcn_global_load_lds(
      (const __attribute__((address_space(1))) void*)g,
      (__attribute__((address_space(3))) void*)lds,
      16, 0, 0);
}

// One launch: vec cvt (blocks 0..8191), wq cvt (blocks 8192..8703), out init
__global__ __launch_bounds__(256) void prep(
    const float* __restrict__ vec, unsigned short* __restrict__ vecbf,
    const float* __restrict__ wq,  unsigned short* __restrict__ wqbf,
    const float* __restrict__ lin_b, float* __restrict__ out)
{
  const int gid = blockIdx.x * 256 + threadIdx.x;
  if (blockIdx.x < 8192) {
    const float4* s = (const float4*)(vec + (size_t)gid * 8);
    float4 a = s[0], b = s[1];
    *(u16x8*)(vecbf + (size_t)gid * 8) = pack8(a, b);
    if (gid < 8192) out[gid] = lin_b[0];
  } else {
    const int i = gid - 8192 * 256;   // 0..131071
    const float4* s = (const float4*)(wq + (size_t)i * 8);
    float4 a = s[0], b = s[1];
    *(u16x8*)(wqbf + (size_t)i * 8) = pack8(a, b);
  }
}

__global__ void init_out(float* __restrict__ out, const float* __restrict__ lin_b) {
  int i = blockIdx.x * 256 + threadIdx.x;
  if (i < 8192) out[i] = lin_b[0];
}

// ------- gemm_q (m97-style): qT(fp8) = wqbf * vecbf^T + bias -------
__global__ __launch_bounds__(256) void gemm_q(
    const unsigned short* __restrict__ A, const unsigned short* __restrict__ Bm,
    const float* __restrict__ bias, unsigned char* __restrict__ qT8)
{
  __shared__ unsigned short As[BM * 32];
  __shared__ unsigned short Bs[BN * 32];

  const int m0 = blockIdx.y * BM;
  const int n0 = blockIdx.x * BN;
  const int t    = threadIdx.x;
  const int lane = t & 63;
  const int wave = t >> 6;
  const int wm = (wave >> 1) * 64;
  const int wn = (wave & 1) * 64;
  const int quad = lane >> 4;
  const int lrow = lane & 15;

  const int srow = t >> 2;                               // 0..63
  const int gcol = (((t & 3) ^ ((srow >> 1) & 3)) << 3); // swizzled col (shorts)
  const unsigned short* gA0 = A  + (size_t)(m0 + srow) * 1024 + gcol;
  const unsigned short* gA1 = gA0 + (size_t)64 * 1024;
  const unsigned short* gB0 = Bm + (size_t)(n0 + srow) * 1024 + gcol;
  const unsigned short* gB1 = gB0 + (size_t)64 * 1024;

  const int rc = (quad ^ ((lrow >> 1) & 3)) << 3;        // shorts

  f32x4 acc[4][4];
#pragma unroll
  for (int i = 0; i < 4; ++i)
#pragma unroll
    for (int j = 0; j < 4; ++j) acc[i][j] = (f32x4){0.f, 0.f, 0.f, 0.f};

  for (int k0 = 0; k0 < 1024; k0 += 32) {
    async16(&As[t * 8],        gA0 + k0);
    async16(&As[2048 + t * 8], gA1 + k0);
    async16(&Bs[t * 8],        gB0 + k0);
    async16(&Bs[2048 + t * 8], gB1 + k0);
    __syncthreads();

    bf16x8 af[4], bfr[4];
#pragma unroll
    for (int i = 0; i < 4; ++i)
      af[i] = *(const bf16x8*)&As[(wm + i * 16 + lrow) * 32 + rc];
#pragma unroll
    for (int j = 0; j < 4; ++j)
      bfr[j] = *(const bf16x8*)&Bs[(wn + j * 16 + lrow) * 32 + rc];
#pragma unroll
    for (int i = 0; i < 4; ++i)
#pragma unroll
      for (int j = 0; j < 4; ++j)
        acc[i][j] = __builtin_amdgcn_mfma_f32_16x16x32_bf16(af[i], bfr[j], acc[i][j], 0, 0, 0);
    __syncthreads();
  }

#pragma unroll
  for (int i = 0; i < 4; ++i) {
    const int mb = m0 + wm + i * 16 + quad * 4;
#pragma unroll
    for (int r = 0; r < 4; ++r) {
      const float bv = bias[mb + r];
#pragma unroll
      for (int j = 0; j < 4; ++j) {
        const int n = n0 + wn + j * 16 + lrow;
        qT8[(size_t)(mb + r) * 16384 + n] = f2fp8(acc[i][j][r] + bv);
      }
    }
  }
}

// ------- fallback gemm_q (fused fp32->bf16 inline), used if ws too small -------
__global__ __launch_bounds__(256) void gemm_q_fused(
    const float* __restrict__ Wq, const float* __restrict__ V,
    const float* __restrict__ bias, unsigned char* __restrict__ qT8)
{
  __shared__ unsigned short As[BM * 32];
  __shared__ unsigned short Bs[BN * 32];

  const int m0 = blockIdx.y * BM;
  const int n0 = blockIdx.x * BN;
  const int t    = threadIdx.x;
  const int lane = t & 63;
  const int wave = t >> 6;
  const int wm = (wave >> 1) * 64;
  const int wn = (wave & 1) * 64;
  const int quad = lane >> 4;
  const int lrow = lane & 15;

  const int sr = t >> 1;
  const int sc = (t & 1) << 4;
  const float* gA = Wq + (size_t)(m0 + sr) * 1024 + sc;
  const float* gB = V  + (size_t)(n0 + sr) * 1024 + sc;

  f32x4 acc[4][4];
#pragma unroll
  for (int i = 0; i < 4; ++i)
#pragma unroll
    for (int j = 0; j < 4; ++j) acc[i][j] = (f32x4){0.f, 0.f, 0.f, 0.f};

  for (int k0 = 0; k0 < 1024; k0 += 32) {
    const float4* a4 = (const float4*)(gA + k0);
    const float4* b4 = (const float4*)(gB + k0);
    float4 av0 = a4[0], av1 = a4[1], av2 = a4[2], av3 = a4[3];
    float4 bv0 = b4[0], bv1 = b4[1], bv2 = b4[2], bv3 = b4[3];
    *(u16x8*)&As[sr * 32 + sc]     = pack8(av0, av1);
    *(u16x8*)&As[sr * 32 + sc + 8] = pack8(av2, av3);
    *(u16x8*)&Bs[sr * 32 + sc]     = pack8(bv0, bv1);
    *(u16x8*)&Bs[sr * 32 + sc + 8] = pack8(bv2, bv3);
    __syncthreads();

    bf16x8 af[4], bfr[4];
#pragma unroll
    for (int i = 0; i < 4; ++i)
      af[i] = *(const bf16x8*)&As[(wm + i * 16 + lrow) * 32 + quad * 8];
#pragma unroll
    for (int j = 0; j < 4; ++j)
      bfr[j] = *(const bf16x8*)&Bs[(wn + j * 16 + lrow) * 32 + quad * 8];
#pragma unroll
    for (int i = 0; i < 4; ++i)
#pragma unroll
      for (int j = 0; j < 4; ++j)
        acc[i][j] = __builtin_amdgcn_mfma_f32_16x16x32_bf16(af[i], bfr[j], acc[i][j], 0, 0, 0);
    __syncthreads();
  }

#pragma unroll
  for (int i = 0; i < 4; ++i) {
    const int mb = m0 + wm + i * 16 + quad * 4;
#pragma unroll
    for (int r = 0; r < 4; ++r) {
      const float bv = bias[mb + r];
#pragma unroll
      for (int j = 0; j < 4; ++j) {
        const int n = n0 + wn + j * 16 + lrow;
        qT8[(size_t)(mb + r) * 16384 + n] = f2fp8(acc[i][j][r] + bv);
      }
    }
  }
}

// ---------- syrk_half8: fp8 staging, symmetric pairs, y-split 128x64 ----------
// qT8 fp8 [1024][16384] (row stride 16384 B); batch bb cols [bb*2048,+2048).
// blockIdx.x in [0,72): pair = x>>1 (ty<=tx), yh = x&1. FULL K=2048 per block.
__global__ __launch_bounds__(256) void syrk_half8(
    const unsigned char* __restrict__ qT8, const float* __restrict__ W,
    float* __restrict__ out)
{
  __shared__ unsigned char As[128 * 64];  // 8 KB
  __shared__ unsigned char Bs[64 * 64];   // 4 KB

  const int bb   = blockIdx.z;
  const int pair = blockIdx.x >> 1;
  const int yh   = blockIdx.x & 1;
  int tx = 0;
  while ((tx + 1) * (tx + 2) / 2 <= pair) ++tx;
  const int ty = pair - tx * (tx + 1) / 2;
  const int x0 = tx * 128;
  const int y0 = ty * 128 + yh * 64;
  const bool diag = (tx == ty);

  const int t    = threadIdx.x;
  const int lane = t & 63;
  const int wave = t >> 6;
  const int wm = (wave >> 1) * 64;   // x offset of wave: 0 or 64
  const int wn = (wave & 1) * 32;    // y offset of wave: 0 or 32
  const int quad = lane >> 4;
  const int lrow = lane & 15;

  // staging: thread covers row t>>2 (A: +64 for issue 2), 16B chunk swizzled
  // by row: g = (t&3) ^ ((row>>2)&3) = (t&3) ^ ((t>>4)&3).
  const int srow = t >> 2;                              // 0..63
  const int g16  = (t & 3) ^ ((t >> 4) & 3);
  const size_t cb = (size_t)bb * 2048 + g16 * 16;
  const unsigned char* gA0 = qT8 + (size_t)(x0 + srow) * 16384 + cb;
  const unsigned char* gA1 = gA0 + (size_t)64 * 16384;
  const unsigned char* gB  = qT8 + (size_t)(y0 + srow) * 16384 + cb;

  // read-side: fragment 8B chunk c = kk*4+quad; G = c>>1, b = c&1;
  // LDS off = ((G ^ f)<<4) + b*8 with f = (lrow>>2)&3 (row-bits, i/wm drop out)
  const int f = (lrow >> 2) & 3;

  f32x4 acc[4][2];
#pragma unroll
  for (int i = 0; i < 4; ++i)
#pragma unroll
    for (int j = 0; j < 2; ++j) acc[i][j] = (f32x4){0.f, 0.f, 0.f, 0.f};

  for (int k0 = 0; k0 < 2048; k0 += 64) {
    async16(&As[t * 16],        gA0 + k0);
    async16(&As[4096 + t * 16], gA1 + k0);
    async16(&Bs[t * 16],        gB  + k0);
    __syncthreads();

#pragma unroll
    for (int kk = 0; kk < 2; ++kk) {
      const int c = kk * 4 + quad;
      const int off = (((c >> 1) ^ f) << 4) + (c & 1) * 8;
      i64 af[4], bfr[2];
#pragma unroll
      for (int i = 0; i < 4; ++i)
        af[i] = *(const i64*)&As[(wm + i * 16 + lrow) * 64 + off];
#pragma unroll
      for (int j = 0; j < 2; ++j)
        bfr[j] = *(const i64*)&Bs[(wn + j * 16 + lrow) * 64 + off];
#pragma unroll
      for (int i = 0; i < 4; ++i)
#pragma unroll
        for (int j = 0; j < 2; ++j)
          acc[i][j] = __builtin_amdgcn_mfma_f32_16x16x32_fp8_fp8(af[i], bfr[j], acc[i][j], 0, 0, 0);
    }
    __syncthreads();
  }

  float* ob = out + bb * 1024;

  // row pass: out[x] += sum_y relu(C[x,y]) * W[y]   (partial over this y-half)
  float wv[2];
#pragma unroll
  for (int j = 0; j < 2; ++j) wv[j] = W[y0 + wn + j * 16 + lrow];

#pragma unroll
  for (int i = 0; i < 4; ++i) {
#pragma unroll
    for (int r = 0; r < 4; ++r) {
      float p = 0.f;
#pragma unroll
      for (int j = 0; j < 2; ++j) {
        float v = acc[i][j][r];
        v = v > 0.f ? v : 0.f;
        p += v * wv[j];
      }
#pragma unroll
      for (int off = 1; off < 16; off <<= 1) p += __shfl_xor(p, off, 64);
      if (lrow == 0)
        atomicAdd(&ob[x0 + wm + i * 16 + quad * 4 + r], p);
    }
  }

  // col pass (off-diagonal pairs only): out[y] += sum_x relu(C[x,y]) * W[x]
  if (!diag) {
    float wx[4][4];
#pragma unroll
    for (int i = 0; i < 4; ++i)
#pragma unroll
      for (int r = 0; r < 4; ++r)
        wx[i][r] = W[x0 + wm + i * 16 + quad * 4 + r];

#pragma unroll
    for (int j = 0; j < 2; ++j) {
      float pc = 0.f;
#pragma unroll
      for (int i = 0; i < 4; ++i)
#pragma unroll
        for (int r = 0; r < 4; ++r) {
          float v = acc[i][j][r];
          v = v > 0.f ? v : 0.f;
          pc += v * wx[i][r];
        }
      pc += __shfl_xor(pc, 16, 64);
      pc += __shfl_xor(pc, 32, 64);
      if (quad == 0)
        atomicAdd(&ob[y0 + wn + j * 16 + lrow], pc);
    }
  }
}

extern "C" void kernel_launch(void* const* d_in, const int* in_sizes, int n_in,
                              void* d_out, int out_size, void* d_ws, size_t ws_size,
                              hipStream_t stream) {
  const float* vec   = (const float*)d_in[0];  // [8,2048,1024]
  const float* wq_w  = (const float*)d_in[1];  // [1024,1024]
  const float* wq_b  = (const float*)d_in[2];  // [1024]
  const float* lin_w = (const float*)d_in[3];  // [1,1024]
  const float* lin_b = (const float*)d_in[4];  // [1]
  float* out = (float*)d_out;                  // [8,1024]

  unsigned char* qT8 = (unsigned char*)d_ws;                       // 16 MiB
  const size_t need = (size_t)(16 + 32 + 2) * 1024 * 1024;

  if (ws_size >= need) {
    unsigned short* vecbf = (unsigned short*)((char*)d_ws + (size_t)16 * 1024 * 1024); // 32 MiB
    unsigned short* wqbf  = vecbf + (size_t)16 * 1024 * 1024;                          // 2 MiB
    prep<<<dim3(8192 + 512), dim3(256), 0, stream>>>(vec, vecbf, wq_w, wqbf, lin_b, out);
    gemm_q<<<dim3(128, 8), dim3(256), 0, stream>>>(wqbf, vecbf, wq_b, qT8);
  } else {
    init_out<<<dim3(32), dim3(256), 0, stream>>>(out, lin_b);
    gemm_q_fused<<<dim3(128, 8), dim3(256), 0, stream>>>(wq_w, vec, wq_b, qT8);
  }
  syrk_half8<<<dim3(72, 1, 8), dim3(256), 0, stream>>>(qT8, lin_w, out);
}

// Round 10
// 168.623 us; speedup vs baseline: 1.2958x; 1.0712x over previous
//
#include <hip/hip_runtime.h>

// B=8, S=2048, IN=1024, H=1024
//   q  = vec @ wq_w^T + wq_b            [B,S,H]
//   ret= relu(q_b^T q_b) per batch      [B,H,H]   (registers only)
//   out= ret @ lin_w + lin_b            [B,H]
//
// Pipeline:
//   prep:       out init + vec/wq fp32->bf16 (one launch)
//   gemm_q:     BK=64 bf16 MFMA GEMM (32 MFMA/barrier-pair); fp8 e4m3 epilogue.
//   syrk_half8: fp8 staging, BK=128 (64 MFMA/barrier-pair), symmetric pairs,
//               y-split 128x64, FULL K (relu nonlinear -> K-split illegal, R5).

typedef short     bf16x8 __attribute__((ext_vector_type(8)));
typedef unsigned short u16x8 __attribute__((ext_vector_type(8)));
typedef float     f32x4 __attribute__((ext_vector_type(4)));
typedef long long i64;

__device__ inline unsigned short f2bf(float f) {
  unsigned int u = __float_as_uint(f);
  u += 0x7fffu + ((u >> 16) & 1u);   // RNE
  return (unsigned short)(u >> 16);
}

__device__ inline u16x8 pack8(float4 a, float4 b) {
  u16x8 r;
  r[0] = f2bf(a.x); r[1] = f2bf(a.y); r[2] = f2bf(a.z); r[3] = f2bf(a.w);
  r[4] = f2bf(b.x); r[5] = f2bf(b.y); r[6] = f2bf(b.z); r[7] = f2bf(b.w);
  return r;
}

__device__ inline unsigned char f2fp8(float v) {
  int pk = __builtin_amdgcn_cvt_pk_fp8_f32(v, v, 0, false);  // RNE, OCP e4m3
  return (unsigned char)(pk & 0xff);
}

__device__ inline void async16(void* lds, const void* g) {
  __builtin_amdgcn_global_load_lds(
      (const __attribute__((address_space(1))) void*)g,
      (__attribute__((address_space(3))) void*)lds,
      16, 0, 0);
}

// One launch: vec cvt (blocks 0..8191), wq cvt (blocks 8192..8703), out init
__global__ __launch_bounds__(256) void prep(
    const float* __restrict__ vec, unsigned short* __restrict__ vecbf,
    const float* __restrict__ wq,  unsigned short* __restrict__ wqbf,
    const float* __restrict__ lin_b, float* __restrict__ out)
{
  const int gid = blockIdx.x * 256 + threadIdx.x;
  if (blockIdx.x < 8192) {
    const float4* s = (const float4*)(vec + (size_t)gid * 8);
    float4 a = s[0], b = s[1];
    *(u16x8*)(vecbf + (size_t)gid * 8) = pack8(a, b);
    if (gid < 8192) out[gid] = lin_b[0];
  } else {
    const int i = gid - 8192 * 256;   // 0..131071
    const float4* s = (const float4*)(wq + (size_t)i * 8);
    float4 a = s[0], b = s[1];
    *(u16x8*)(wqbf + (size_t)i * 8) = pack8(a, b);
  }
}

__global__ void init_out(float* __restrict__ out, const float* __restrict__ lin_b) {
  int i = blockIdx.x * 256 + threadIdx.x;
  if (i < 8192) out[i] = lin_b[0];
}

// ------- gemm_q BK=64: qT8(fp8) = wqbf * vecbf^T + bias -------
// A=wqbf [1024,1024] bf16, B=vecbf [16384,1024] bf16, both K-contig.
__global__ __launch_bounds__(256) void gemm_q(
    const unsigned short* __restrict__ A, const unsigned short* __restrict__ Bm,
    const float* __restrict__ bias, unsigned char* __restrict__ qT8)
{
  __shared__ unsigned short As[128 * 64];   // 16 KB
  __shared__ unsigned short Bs[128 * 64];   // 16 KB

  const int m0 = blockIdx.y * 128;
  const int n0 = blockIdx.x * 128;
  const int t    = threadIdx.x;
  const int lane = t & 63;
  const int wave = t >> 6;
  const int wm = (wave >> 1) * 64;
  const int wn = (wave & 1) * 64;
  const int quad = lane >> 4;
  const int lrow = lane & 15;

  // staging (R4 syrk_dot proven pattern): issue p covers rows p*32 + (t>>3),
  // global 8-short chunk (t&7)^(row&7) lands at LDS slot t&7.
  const int srow = t >> 3;                              // 0..31
  const int gcol = (((t & 7) ^ (srow & 7)) << 3);       // shorts
  const unsigned short* gA = A  + (size_t)(m0 + srow) * 1024 + gcol;
  const unsigned short* gB = Bm + (size_t)(n0 + srow) * 1024 + gcol;

  f32x4 acc[4][4];
#pragma unroll
  for (int i = 0; i < 4; ++i)
#pragma unroll
    for (int j = 0; j < 4; ++j) acc[i][j] = (f32x4){0.f, 0.f, 0.f, 0.f};

  for (int k0 = 0; k0 < 1024; k0 += 64) {
#pragma unroll
    for (int p = 0; p < 4; ++p)
      async16(&As[p * 2048 + t * 8], gA + (size_t)p * 32 * 1024 + k0);
#pragma unroll
    for (int p = 0; p < 4; ++p)
      async16(&Bs[p * 2048 + t * 8], gB + (size_t)p * 32 * 1024 + k0);
    __syncthreads();

#pragma unroll
    for (int kk = 0; kk < 2; ++kk) {
      const int rc = (((kk * 4 + quad) ^ (lrow & 7)) << 3);  // shorts
      bf16x8 af[4], bfr[4];
#pragma unroll
      for (int i = 0; i < 4; ++i)
        af[i] = *(const bf16x8*)&As[(wm + i * 16 + lrow) * 64 + rc];
#pragma unroll
      for (int j = 0; j < 4; ++j)
        bfr[j] = *(const bf16x8*)&Bs[(wn + j * 16 + lrow) * 64 + rc];
#pragma unroll
      for (int i = 0; i < 4; ++i)
#pragma unroll
        for (int j = 0; j < 4; ++j)
          acc[i][j] = __builtin_amdgcn_mfma_f32_16x16x32_bf16(af[i], bfr[j], acc[i][j], 0, 0, 0);
    }
    __syncthreads();
  }

#pragma unroll
  for (int i = 0; i < 4; ++i) {
    const int mb = m0 + wm + i * 16 + quad * 4;
#pragma unroll
    for (int r = 0; r < 4; ++r) {
      const float bv = bias[mb + r];
#pragma unroll
      for (int j = 0; j < 4; ++j) {
        const int n = n0 + wn + j * 16 + lrow;
        qT8[(size_t)(mb + r) * 16384 + n] = f2fp8(acc[i][j][r] + bv);
      }
    }
  }
}

// ------- fallback gemm_q (fused fp32->bf16 inline), used if ws too small -------
__global__ __launch_bounds__(256) void gemm_q_fused(
    const float* __restrict__ Wq, const float* __restrict__ V,
    const float* __restrict__ bias, unsigned char* __restrict__ qT8)
{
  __shared__ unsigned short As[128 * 32];
  __shared__ unsigned short Bs[128 * 32];

  const int m0 = blockIdx.y * 128;
  const int n0 = blockIdx.x * 128;
  const int t    = threadIdx.x;
  const int lane = t & 63;
  const int wave = t >> 6;
  const int wm = (wave >> 1) * 64;
  const int wn = (wave & 1) * 64;
  const int quad = lane >> 4;
  const int lrow = lane & 15;

  const int sr = t >> 1;
  const int sc = (t & 1) << 4;
  const float* gA = Wq + (size_t)(m0 + sr) * 1024 + sc;
  const float* gB = V  + (size_t)(n0 + sr) * 1024 + sc;

  f32x4 acc[4][4];
#pragma unroll
  for (int i = 0; i < 4; ++i)
#pragma unroll
    for (int j = 0; j < 4; ++j) acc[i][j] = (f32x4){0.f, 0.f, 0.f, 0.f};

  for (int k0 = 0; k0 < 1024; k0 += 32) {
    const float4* a4 = (const float4*)(gA + k0);
    const float4* b4 = (const float4*)(gB + k0);
    float4 av0 = a4[0], av1 = a4[1], av2 = a4[2], av3 = a4[3];
    float4 bv0 = b4[0], bv1 = b4[1], bv2 = b4[2], bv3 = b4[3];
    *(u16x8*)&As[sr * 32 + sc]     = pack8(av0, av1);
    *(u16x8*)&As[sr * 32 + sc + 8] = pack8(av2, av3);
    *(u16x8*)&Bs[sr * 32 + sc]     = pack8(bv0, bv1);
    *(u16x8*)&Bs[sr * 32 + sc + 8] = pack8(bv2, bv3);
    __syncthreads();

    bf16x8 af[4], bfr[4];
#pragma unroll
    for (int i = 0; i < 4; ++i)
      af[i] = *(const bf16x8*)&As[(wm + i * 16 + lrow) * 32 + quad * 8];
#pragma unroll
    for (int j = 0; j < 4; ++j)
      bfr[j] = *(const bf16x8*)&Bs[(wn + j * 16 + lrow) * 32 + quad * 8];
#pragma unroll
    for (int i = 0; i < 4; ++i)
#pragma unroll
      for (int j = 0; j < 4; ++j)
        acc[i][j] = __builtin_amdgcn_mfma_f32_16x16x32_bf16(af[i], bfr[j], acc[i][j], 0, 0, 0);
    __syncthreads();
  }

#pragma unroll
  for (int i = 0; i < 4; ++i) {
    const int mb = m0 + wm + i * 16 + quad * 4;
#pragma unroll
    for (int r = 0; r < 4; ++r) {
      const float bv = bias[mb + r];
#pragma unroll
      for (int j = 0; j < 4; ++j) {
        const int n = n0 + wn + j * 16 + lrow;
        qT8[(size_t)(mb + r) * 16384 + n] = f2fp8(acc[i][j][r] + bv);
      }
    }
  }
}

// ---------- syrk_half8: fp8 staging, BK=128, symmetric pairs, y-split ----------
// qT8 fp8 [1024][16384]; batch bb cols [bb*2048,+2048). FULL K=2048 per block.
// blockIdx.x in [0,72): pair = x>>1 (ty<=tx over 8 128-tiles), yh = x&1.
__global__ __launch_bounds__(256) void syrk_half8(
    const unsigned char* __restrict__ qT8, const float* __restrict__ W,
    float* __restrict__ out)
{
  __shared__ unsigned char As[128 * 128];  // 16 KB
  __shared__ unsigned char Bs[64 * 128];   // 8 KB

  const int bb   = blockIdx.z;
  const int pair = blockIdx.x >> 1;
  const int yh   = blockIdx.x & 1;
  int tx = 0;
  while ((tx + 1) * (tx + 2) / 2 <= pair) ++tx;
  const int ty = pair - tx * (tx + 1) / 2;
  const int x0 = tx * 128;
  const int y0 = ty * 128 + yh * 64;
  const bool diag = (tx == ty);

  const int t    = threadIdx.x;
  const int lane = t & 63;
  const int wave = t >> 6;
  const int wm = (wave >> 1) * 64;   // x offset of wave: 0 or 64
  const int wn = (wave & 1) * 32;    // y offset of wave: 0 or 32
  const int quad = lane >> 4;
  const int lrow = lane & 15;

  // staging: issue p covers rows p*32 + (t>>3); global 16B chunk
  // (t&7)^(row&7) lands at LDS slot t&7.
  const int srow = t >> 3;                              // 0..31
  const int g16  = (t & 7) ^ (srow & 7);
  const size_t cb = (size_t)bb * 2048 + g16 * 16;
  const unsigned char* gA = qT8 + (size_t)(x0 + srow) * 16384 + cb;
  const unsigned char* gB = qT8 + (size_t)(y0 + srow) * 16384 + cb;

  f32x4 acc[4][2];
#pragma unroll
  for (int i = 0; i < 4; ++i)
#pragma unroll
    for (int j = 0; j < 2; ++j) acc[i][j] = (f32x4){0.f, 0.f, 0.f, 0.f};

  for (int k0 = 0; k0 < 2048; k0 += 128) {
#pragma unroll
    for (int p = 0; p < 4; ++p)
      async16(&As[p * 4096 + t * 16], gA + (size_t)p * 32 * 16384 + k0);
#pragma unroll
    for (int p = 0; p < 2; ++p)
      async16(&Bs[p * 4096 + t * 16], gB + (size_t)p * 32 * 16384 + k0);
    __syncthreads();

#pragma unroll
    for (int kk = 0; kk < 4; ++kk) {
      const int c = kk * 4 + quad;                       // 8B chunk 0..15
      const int off = (((c >> 1) ^ (lrow & 7)) << 4) + (c & 1) * 8;
      i64 af[4], bfr[2];
#pragma unroll
      for (int i = 0; i < 4; ++i)
        af[i] = *(const i64*)&As[(wm + i * 16 + lrow) * 128 + off];
#pragma unroll
      for (int j = 0; j < 2; ++j)
        bfr[j] = *(const i64*)&Bs[(wn + j * 16 + lrow) * 128 + off];
#pragma unroll
      for (int i = 0; i < 4; ++i)
#pragma unroll
        for (int j = 0; j < 2; ++j)
          acc[i][j] = __builtin_amdgcn_mfma_f32_16x16x32_fp8_fp8(af[i], bfr[j], acc[i][j], 0, 0, 0);
    }
    __syncthreads();
  }

  float* ob = out + bb * 1024;

  // row pass: out[x] += sum_y relu(C[x,y]) * W[y]   (partial over this y-half)
  float wv[2];
#pragma unroll
  for (int j = 0; j < 2; ++j) wv[j] = W[y0 + wn + j * 16 + lrow];

#pragma unroll
  for (int i = 0; i < 4; ++i) {
#pragma unroll
    for (int r = 0; r < 4; ++r) {
      float p = 0.f;
#pragma unroll
      for (int j = 0; j < 2; ++j) {
        float v = acc[i][j][r];
        v = v > 0.f ? v : 0.f;
        p += v * wv[j];
      }
#pragma unroll
      for (int off = 1; off < 16; off <<= 1) p += __shfl_xor(p, off, 64);
      if (lrow == 0)
        atomicAdd(&ob[x0 + wm + i * 16 + quad * 4 + r], p);
    }
  }

  // col pass (off-diagonal pairs only): out[y] += sum_x relu(C[x,y]) * W[x]
  if (!diag) {
    float wx[4][4];
#pragma unroll
    for (int i = 0; i < 4; ++i)
#pragma unroll
      for (int r = 0; r < 4; ++r)
        wx[i][r] = W[x0 + wm + i * 16 + quad * 4 + r];

#pragma unroll
    for (int j = 0; j < 2; ++j) {
      float pc = 0.f;
#pragma unroll
      for (int i = 0; i < 4; ++i)
#pragma unroll
        for (int r = 0; r < 4; ++r) {
          float v = acc[i][j][r];
          v = v > 0.f ? v : 0.f;
          pc += v * wx[i][r];
        }
      pc += __shfl_xor(pc, 16, 64);
      pc += __shfl_xor(pc, 32, 64);
      if (quad == 0)
        atomicAdd(&ob[y0 + wn + j * 16 + lrow], pc);
    }
  }
}

extern "C" void kernel_launch(void* const* d_in, const int* in_sizes, int n_in,
                              void* d_out, int out_size, void* d_ws, size_t ws_size,
                              hipStream_t stream) {
  const float* vec   = (const float*)d_in[0];  // [8,2048,1024]
  const float* wq_w  = (const float*)d_in[1];  // [1024,1024]
  const float* wq_b  = (const float*)d_in[2];  // [1024]
  const float* lin_w = (const float*)d_in[3];  // [1,1024]
  const float* lin_b = (const float*)d_in[4];  // [1]
  float* out = (float*)d_out;                  // [8,1024]

  unsigned char* qT8 = (unsigned char*)d_ws;                       // 16 MiB
  const size_t need = (size_t)(16 + 32 + 2) * 1024 * 1024;

  if (ws_size >= need) {
    unsigned short* vecbf = (unsigned short*)((char*)d_ws + (size_t)16 * 1024 * 1024); // 32 MiB
    unsigned short* wqbf  = vecbf + (size_t)16 * 1024 * 1024;                          // 2 MiB
    prep<<<dim3(8192 + 512), dim3(256), 0, stream>>>(vec, vecbf, wq_w, wqbf, lin_b, out);
    gemm_q<<<dim3(128, 8), dim3(256), 0, stream>>>(wqbf, vecbf, wq_b, qT8);
  } else {
    init_out<<<dim3(32), dim3(256), 0, stream>>>(out, lin_b);
    gemm_q_fused<<<dim3(128, 8), dim3(256), 0, stream>>>(wq_w, vec, wq_b, qT8);
  }
  syrk_half8<<<dim3(72, 1, 8), dim3(256), 0, stream>>>(qT8, lin_w, out);
}